// Round 14
// baseline (160.248 us; speedup 1.0000x reference)
//
#include <hip/hip_runtime.h>
#include <math.h>

#define N_NODES 50000
#define M_NBR 16
#define D 128
#define E 64

typedef __attribute__((ext_vector_type(8))) __bf16 bf16x8;
typedef __attribute__((ext_vector_type(4))) float f32x4;

// Fragment-permuted weight storage (bf16):
//   flat = (((dt*NKT + kt)*4 + c)*16 + r)*8 + j
// holds W_natural[k = kt*32 + c*8 + j][d = dt*16 + r].

// ---------------------------------------------------------------------------
// K0: build fragment-permuted bf16 weights.  (unchanged, known-good)
// ---------------------------------------------------------------------------
__global__ __launch_bounds__(256) void k_prep(const float* __restrict__ W1,
                                              const float* __restrict__ W2,
                                              __bf16* __restrict__ w1a_f,
                                              __bf16* __restrict__ w1b_f,
                                              __bf16* __restrict__ w1c_f,
                                              __bf16* __restrict__ w2_f) {
  const int t = blockIdx.x * 256 + threadIdx.x;
  if (t < 16384) {                       // W1a
    const int j = t & 7, r = (t >> 3) & 15, c = (t >> 7) & 3, q = t >> 9;
    const int kt = q & 3, dt = q >> 2;
    w1a_f[t] = (__bf16)W1[(kt * 32 + c * 8 + j) * 128 + dt * 16 + r];
  } else if (t < 32768) {                // W1b
    const int u = t - 16384;
    const int j = u & 7, r = (u >> 3) & 15, c = (u >> 7) & 3, q = u >> 9;
    const int kt = q & 3, dt = q >> 2;
    w1b_f[u] = (__bf16)W1[(128 + kt * 32 + c * 8 + j) * 128 + dt * 16 + r];
  } else if (t < 40960) {                // W1c (NKT=2)
    const int u = t - 32768;
    const int j = u & 7, r = (u >> 3) & 15, c = (u >> 7) & 3, q = u >> 9;
    const int kt = q & 1, dt = q >> 1;
    w1c_f[u] = (__bf16)W1[(256 + kt * 32 + c * 8 + j) * 128 + dt * 16 + r];
  } else if (t < 57344) {                // W2, permuted k
    const int u = t - 40960;
    const int j = u & 7, r = (u >> 3) & 15, c = (u >> 7) & 3, q = u >> 9;
    const int kt = q & 3, dt = q >> 2;
    const int i = kt * 32 + c * 8 + j;             // stored-k
    const int ak = (i & 7) * 16 + (i >> 3);        // natural k in hsum row
    w2_f[u] = (__bf16)W2[ak * 128 + dt * 16 + r];
  }
}

// ---------------------------------------------------------------------------
// K1: fused LayerNorm + dual GEMM via MFMA.  (unchanged, known-good)
// ---------------------------------------------------------------------------
__global__ __launch_bounds__(256) void k_t12f(const float* __restrict__ x,
                                              const float* __restrict__ sc,
                                              const float* __restrict__ bi,
                                              const __bf16* __restrict__ w1a_f,
                                              const __bf16* __restrict__ w1b_f,
                                              const float* __restrict__ b1,
                                              float* __restrict__ t1p,
                                              __bf16* __restrict__ t2bp) {
  const int wave = blockIdx.x * 4 + (threadIdx.x >> 6);
  if (wave >= N_NODES / 16) return;
  const int lane = threadIdx.x & 63;
  const int r = lane & 15, c = lane >> 4;
  const int node0 = wave * 16;

  const float* row = x + (size_t)(node0 + r) * 128 + c * 8;
  f32x4 va[8];
  #pragma unroll
  for (int kt = 0; kt < 4; ++kt) {
    va[2 * kt]     = *(const f32x4*)(row + kt * 32);
    va[2 * kt + 1] = *(const f32x4*)(row + kt * 32 + 4);
  }
  float s = 0.f;
  #pragma unroll
  for (int q = 0; q < 8; ++q) s += va[q][0] + va[q][1] + va[q][2] + va[q][3];
  s += __shfl_xor(s, 16, 64);
  s += __shfl_xor(s, 32, 64);
  const float mu = s * (1.0f / 128.0f);
  float qs = 0.f;
  #pragma unroll
  for (int q = 0; q < 8; ++q) {
    #pragma unroll
    for (int e = 0; e < 4; ++e) { const float dxx = va[q][e] - mu; qs += dxx * dxx; }
  }
  qs += __shfl_xor(qs, 16, 64);
  qs += __shfl_xor(qs, 32, 64);
  const float rs = rsqrtf(qs * (1.0f / 128.0f) + 1e-6f);

  bf16x8 af[4];
  #pragma unroll
  for (int kt = 0; kt < 4; ++kt) {
    const f32x4 s_lo = *(const f32x4*)(sc + kt * 32 + c * 8);
    const f32x4 s_hi = *(const f32x4*)(sc + kt * 32 + c * 8 + 4);
    const f32x4 b_lo = *(const f32x4*)(bi + kt * 32 + c * 8);
    const f32x4 b_hi = *(const f32x4*)(bi + kt * 32 + c * 8 + 4);
    #pragma unroll
    for (int e = 0; e < 4; ++e) {
      af[kt][e]     = (__bf16)(((va[2 * kt][e]     - mu) * rs) * s_lo[e] + b_lo[e]);
      af[kt][4 + e] = (__bf16)(((va[2 * kt + 1][e] - mu) * rs) * s_hi[e] + b_hi[e]);
    }
  }

  const bf16x8* wa = (const bf16x8*)w1a_f;
  const bf16x8* wb = (const bf16x8*)w1b_f;
  f32x4 acc1[8], acc2[8];
  #pragma unroll
  for (int dt = 0; dt < 8; ++dt) { acc1[dt] = (f32x4){0,0,0,0}; acc2[dt] = (f32x4){0,0,0,0}; }
  #pragma unroll
  for (int dt = 0; dt < 8; ++dt) {
    #pragma unroll
    for (int kt = 0; kt < 4; ++kt) {
      const bf16x8 bfa = wa[(dt * 4 + kt) * 64 + c * 16 + r];
      acc1[dt] = __builtin_amdgcn_mfma_f32_16x16x32_bf16(af[kt], bfa, acc1[dt], 0, 0, 0);
      const bf16x8 bfb = wb[(dt * 4 + kt) * 64 + c * 16 + r];
      acc2[dt] = __builtin_amdgcn_mfma_f32_16x16x32_bf16(af[kt], bfb, acc2[dt], 0, 0, 0);
    }
  }

  float b1v[8];
  #pragma unroll
  for (int dt = 0; dt < 8; ++dt) b1v[dt] = b1[dt * 16 + r];
  #pragma unroll
  for (int j = 0; j < 4; ++j) {
    const int node = node0 + c * 4 + j;
    f32x4 t1lo, t1hi;
    bf16x8 t2v;
    #pragma unroll
    for (int dt = 0; dt < 4; ++dt)  t1lo[dt]     = acc1[dt][j] + b1v[dt];
    #pragma unroll
    for (int dt = 4; dt < 8; ++dt)  t1hi[dt - 4] = acc1[dt][j] + b1v[dt];
    #pragma unroll
    for (int dt = 0; dt < 8; ++dt)  t2v[dt] = (__bf16)acc2[dt][j];
    *(f32x4*)(t1p + (size_t)node * 128 + r * 8)     = t1lo;
    *(f32x4*)(t1p + (size_t)node * 128 + r * 8 + 4) = t1hi;
    *(bf16x8*)(t2bp + (size_t)node * 128 + r * 8)   = t2v;
  }
}

// ---------------------------------------------------------------------------
// K2: edge GEMM, R14: pure straight-line wave, ZERO barriers, ZERO LDS.
// One wave = one node.  All ~27 VMEM loads issued up-front and concurrently
// in flight (idx -> tg is the only dependent chain).  W1c in registers via
// 16 independent 16B loads (L1/L2 broadcast-hot, every wave reads the same
// 16KB).  Two latency windows per wave; hidden by wave churn.
// ---------------------------------------------------------------------------
__global__ __launch_bounds__(256, 3) void k_edge(const float* __restrict__ nbr,
                                                 const int* __restrict__ idx,
                                                 const float* __restrict__ t1p,
                                                 const __bf16* __restrict__ t2bp,
                                                 const __bf16* __restrict__ w1c_f,
                                                 float* __restrict__ hsum_p) {
  const int lane = threadIdx.x & 63;
  const int wid  = threadIdx.x >> 6;
  const int r = lane & 15, c = lane >> 4;
  const int n = blockIdx.x * 4 + wid;

  // ---- idx first (heads the only dependent chain)
  const int4 g = *(const int4*)(idx + n * M_NBR + c * 4);

  // ---- independent loads: A rows, t1 row, all 16 W1c fragments
  const float* arow = nbr + (size_t)n * (M_NBR * E) + r * E + c * 8;
  const f32x4 a0 = *(const f32x4*)(arow);
  const f32x4 a1 = *(const f32x4*)(arow + 4);
  const f32x4 a2 = *(const f32x4*)(arow + 32);
  const f32x4 a3 = *(const f32x4*)(arow + 36);
  const f32x4 t1lo = *(const f32x4*)(t1p + (size_t)n * 128 + r * 8);
  const f32x4 t1hi = *(const f32x4*)(t1p + (size_t)n * 128 + r * 8 + 4);

  const bf16x8* wc = (const bf16x8*)w1c_f;
  bf16x8 bfrag[8][2];
  #pragma unroll
  for (int dt = 0; dt < 8; ++dt) {
    bfrag[dt][0] = wc[(dt * 2 + 0) * 64 + c * 16 + r];
    bfrag[dt][1] = wc[(dt * 2 + 1) * 64 + c * 16 + r];
  }

  // ---- gathers (depend only on g; issued while everything above flies)
  const bf16x8 tg0 = *(const bf16x8*)(t2bp + (size_t)g.x * 128 + r * 8);
  const bf16x8 tg1 = *(const bf16x8*)(t2bp + (size_t)g.y * 128 + r * 8);
  const bf16x8 tg2 = *(const bf16x8*)(t2bp + (size_t)g.z * 128 + r * 8);
  const bf16x8 tg3 = *(const bf16x8*)(t2bp + (size_t)g.w * 128 + r * 8);

  // ---- A fragments
  bf16x8 af0, af1;
  #pragma unroll
  for (int e = 0; e < 4; ++e) {
    af0[e] = (__bf16)a0[e]; af0[4 + e] = (__bf16)a1[e];
    af1[e] = (__bf16)a2[e]; af1[4 + e] = (__bf16)a3[e];
  }

  // ---- 16 MFMAs, all-register operands
  f32x4 acc[8];
  #pragma unroll
  for (int dt = 0; dt < 8; ++dt) acc[dt] = (f32x4){0, 0, 0, 0};
  #pragma unroll
  for (int dt = 0; dt < 8; ++dt) {
    acc[dt] = __builtin_amdgcn_mfma_f32_16x16x32_bf16(af0, bfrag[dt][0], acc[dt], 0, 0, 0);
    acc[dt] = __builtin_amdgcn_mfma_f32_16x16x32_bf16(af1, bfrag[dt][1], acc[dt], 0, 0, 0);
  }

  // ---- epilogue: +t1(+b1) +t2[g], silu, reduce over c-groups, store
  float ssum[8];
  #pragma unroll
  for (int dt = 0; dt < 8; ++dt) {
    const float tb = (dt < 4) ? t1lo[dt & 3] : t1hi[dt & 3];
    float s = 0.f;
    { const float h = acc[dt][0] + tb + (float)tg0[dt]; s += __fdividef(h, 1.0f + __expf(-h)); }
    { const float h = acc[dt][1] + tb + (float)tg1[dt]; s += __fdividef(h, 1.0f + __expf(-h)); }
    { const float h = acc[dt][2] + tb + (float)tg2[dt]; s += __fdividef(h, 1.0f + __expf(-h)); }
    { const float h = acc[dt][3] + tb + (float)tg3[dt]; s += __fdividef(h, 1.0f + __expf(-h)); }
    s += __shfl_xor(s, 16, 64);
    s += __shfl_xor(s, 32, 64);
    ssum[dt] = s;
  }
  if (lane < 16) {
    f32x4 o_lo, o_hi;
    #pragma unroll
    for (int dt = 0; dt < 4; ++dt) { o_lo[dt] = ssum[dt]; o_hi[dt] = ssum[dt + 4]; }
    *(f32x4*)(hsum_p + (size_t)n * 128 + r * 8)     = o_lo;
    *(f32x4*)(hsum_p + (size_t)n * 128 + r * 8 + 4) = o_hi;
  }
}

// ---------------------------------------------------------------------------
// K3: out = x + hsum@W2 + 16*b2 via MFMA.  (unchanged, known-good)
// ---------------------------------------------------------------------------
__global__ __launch_bounds__(256) void k_out(const float* __restrict__ hsum_p,
                                             const __bf16* __restrict__ w2_f,
                                             const float* __restrict__ b2,
                                             const float* __restrict__ x,
                                             float* __restrict__ out) {
  const int wave = blockIdx.x * 4 + (threadIdx.x >> 6);
  if (wave >= N_NODES / 16) return;
  const int lane = threadIdx.x & 63;
  const int r = lane & 15, c = lane >> 4;
  const int node0 = wave * 16;

  const float* row = hsum_p + (size_t)(node0 + r) * 128 + c * 8;
  bf16x8 af[4];
  #pragma unroll
  for (int kt = 0; kt < 4; ++kt) {
    const f32x4 lo = *(const f32x4*)(row + kt * 32);
    const f32x4 hi = *(const f32x4*)(row + kt * 32 + 4);
    #pragma unroll
    for (int e = 0; e < 4; ++e) { af[kt][e] = (__bf16)lo[e]; af[kt][4 + e] = (__bf16)hi[e]; }
  }

  const bf16x8* w2 = (const bf16x8*)w2_f;
  f32x4 acc[8];
  #pragma unroll
  for (int dt = 0; dt < 8; ++dt) acc[dt] = (f32x4){0,0,0,0};
  #pragma unroll
  for (int dt = 0; dt < 8; ++dt) {
    #pragma unroll
    for (int kt = 0; kt < 4; ++kt) {
      const bf16x8 bf = w2[(dt * 4 + kt) * 64 + c * 16 + r];
      acc[dt] = __builtin_amdgcn_mfma_f32_16x16x32_bf16(af[kt], bf, acc[dt], 0, 0, 0);
    }
  }

  float b2v[8];
  #pragma unroll
  for (int dt = 0; dt < 8; ++dt) b2v[dt] = 16.0f * b2[dt * 16 + r];
  #pragma unroll
  for (int j = 0; j < 4; ++j) {
    const int node = node0 + c * 4 + j;
    #pragma unroll
    for (int dt = 0; dt < 8; ++dt) {
      const size_t o = (size_t)node * 128 + dt * 16 + r;
      out[o] = x[o] + acc[dt][j] + b2v[dt];
    }
  }
}

// ---------------------------------------------------------------------------
extern "C" void kernel_launch(void* const* d_in, const int* in_sizes, int n_in,
                              void* d_out, int out_size, void* d_ws, size_t ws_size,
                              hipStream_t stream) {
  const float* x        = (const float*)d_in[0];
  const float* nbr_fea  = (const float*)d_in[1];
  const int*   nbr_idx  = (const int*)d_in[2];
  const float* ln_scale = (const float*)d_in[3];
  const float* ln_bias  = (const float*)d_in[4];
  const float* W1       = (const float*)d_in[5];
  const float* b1       = (const float*)d_in[6];
  const float* W2       = (const float*)d_in[7];
  const float* b2       = (const float*)d_in[8];
  float* out = (float*)d_out;

  char* ws = (char*)d_ws;
  float*  t1p    = (float*)(ws);                       // 25,600,000 B
  float*  hsum_p = (float*)(ws + 25600000);            // 25,600,000 B
  __bf16* t2bp   = (__bf16*)(ws + 51200000);           // 12,800,000 B
  __bf16* w1a_f  = (__bf16*)(ws + 64000000);           //     32,768 B
  __bf16* w1b_f  = (__bf16*)(ws + 64032768);           //     32,768 B
  __bf16* w1c_f  = (__bf16*)(ws + 64065536);           //     16,384 B
  __bf16* w2_f   = (__bf16*)(ws + 64081920);           //     32,768 B

  k_prep <<<224, 256, 0, stream>>>(W1, W2, w1a_f, w1b_f, w1c_f, w2_f);
  k_t12f <<<(N_NODES / 16 + 3) / 4, 256, 0, stream>>>(x, ln_scale, ln_bias,
                                                      w1a_f, w1b_f, b1, t1p, t2bp);
  k_edge <<<N_NODES / 4, 256, 0, stream>>>(nbr_fea, nbr_idx, t1p, t2bp, w1c_f, hsum_p);
  k_out  <<<(N_NODES / 16 + 3) / 4, 256, 0, stream>>>(hsum_p, w2_f, b2, x, out);
}

// Round 15
// 122.717 us; speedup vs baseline: 1.3058x; 1.3058x over previous
//
#include <hip/hip_runtime.h>
#include <math.h>

#define N_NODES 50000
#define M_NBR 16
#define D 128
#define E 64

typedef __attribute__((ext_vector_type(8))) __bf16 bf16x8;
typedef __attribute__((ext_vector_type(4))) float f32x4;

// async global->LDS (HW: per-lane global src; wave-uniform LDS base + lane*16)
__device__ __forceinline__ void gload16(const void* g, void* l) {
  __builtin_amdgcn_global_load_lds(
      (const __attribute__((address_space(1))) void*)g,
      (__attribute__((address_space(3))) void*)l, 16, 0, 0);
}

// W1c LDS swizzle: stored[s] = orig[s ^ (((s>>7)&7)<<4)]  (involution; XORs
// bits {7,8,9} = {r3,c0,c1} into bank bits {4,5,6} -> conflict-free b128 reads)
__device__ __forceinline__ int swz(int o) { return o ^ (((o >> 7) & 7) << 4); }

// Fragment-permuted weight storage (bf16):
//   flat = (((dt*NKT + kt)*4 + c)*16 + r)*8 + j
// holds W_natural[k = kt*32 + c*8 + j][d = dt*16 + r].

// ---------------------------------------------------------------------------
// K0: build fragment-permuted bf16 weights.  (unchanged, known-good)
// ---------------------------------------------------------------------------
__global__ __launch_bounds__(256) void k_prep(const float* __restrict__ W1,
                                              const float* __restrict__ W2,
                                              __bf16* __restrict__ w1a_f,
                                              __bf16* __restrict__ w1b_f,
                                              __bf16* __restrict__ w1c_f,
                                              __bf16* __restrict__ w2_f) {
  const int t = blockIdx.x * 256 + threadIdx.x;
  if (t < 16384) {                       // W1a
    const int j = t & 7, r = (t >> 3) & 15, c = (t >> 7) & 3, q = t >> 9;
    const int kt = q & 3, dt = q >> 2;
    w1a_f[t] = (__bf16)W1[(kt * 32 + c * 8 + j) * 128 + dt * 16 + r];
  } else if (t < 32768) {                // W1b
    const int u = t - 16384;
    const int j = u & 7, r = (u >> 3) & 15, c = (u >> 7) & 3, q = u >> 9;
    const int kt = q & 3, dt = q >> 2;
    w1b_f[u] = (__bf16)W1[(128 + kt * 32 + c * 8 + j) * 128 + dt * 16 + r];
  } else if (t < 40960) {                // W1c (NKT=2)
    const int u = t - 32768;
    const int j = u & 7, r = (u >> 3) & 15, c = (u >> 7) & 3, q = u >> 9;
    const int kt = q & 1, dt = q >> 1;
    w1c_f[u] = (__bf16)W1[(256 + kt * 32 + c * 8 + j) * 128 + dt * 16 + r];
  } else if (t < 57344) {                // W2, permuted k
    const int u = t - 40960;
    const int j = u & 7, r = (u >> 3) & 15, c = (u >> 7) & 3, q = u >> 9;
    const int kt = q & 3, dt = q >> 2;
    const int i = kt * 32 + c * 8 + j;             // stored-k
    const int ak = (i & 7) * 16 + (i >> 3);        // natural k in hsum row
    w2_f[u] = (__bf16)W2[ak * 128 + dt * 16 + r];
  }
}

// ---------------------------------------------------------------------------
// K1: fused LayerNorm + dual GEMM via MFMA.  R15: t1 output now bf16.
// ---------------------------------------------------------------------------
__global__ __launch_bounds__(256) void k_t12f(const float* __restrict__ x,
                                              const float* __restrict__ sc,
                                              const float* __restrict__ bi,
                                              const __bf16* __restrict__ w1a_f,
                                              const __bf16* __restrict__ w1b_f,
                                              const float* __restrict__ b1,
                                              __bf16* __restrict__ t1bp,
                                              __bf16* __restrict__ t2bp) {
  const int wave = blockIdx.x * 4 + (threadIdx.x >> 6);
  if (wave >= N_NODES / 16) return;
  const int lane = threadIdx.x & 63;
  const int r = lane & 15, c = lane >> 4;
  const int node0 = wave * 16;

  const float* row = x + (size_t)(node0 + r) * 128 + c * 8;
  f32x4 va[8];
  #pragma unroll
  for (int kt = 0; kt < 4; ++kt) {
    va[2 * kt]     = *(const f32x4*)(row + kt * 32);
    va[2 * kt + 1] = *(const f32x4*)(row + kt * 32 + 4);
  }
  float s = 0.f;
  #pragma unroll
  for (int q = 0; q < 8; ++q) s += va[q][0] + va[q][1] + va[q][2] + va[q][3];
  s += __shfl_xor(s, 16, 64);
  s += __shfl_xor(s, 32, 64);
  const float mu = s * (1.0f / 128.0f);
  float qs = 0.f;
  #pragma unroll
  for (int q = 0; q < 8; ++q) {
    #pragma unroll
    for (int e = 0; e < 4; ++e) { const float dxx = va[q][e] - mu; qs += dxx * dxx; }
  }
  qs += __shfl_xor(qs, 16, 64);
  qs += __shfl_xor(qs, 32, 64);
  const float rs = rsqrtf(qs * (1.0f / 128.0f) + 1e-6f);

  bf16x8 af[4];
  #pragma unroll
  for (int kt = 0; kt < 4; ++kt) {
    const f32x4 s_lo = *(const f32x4*)(sc + kt * 32 + c * 8);
    const f32x4 s_hi = *(const f32x4*)(sc + kt * 32 + c * 8 + 4);
    const f32x4 b_lo = *(const f32x4*)(bi + kt * 32 + c * 8);
    const f32x4 b_hi = *(const f32x4*)(bi + kt * 32 + c * 8 + 4);
    #pragma unroll
    for (int e = 0; e < 4; ++e) {
      af[kt][e]     = (__bf16)(((va[2 * kt][e]     - mu) * rs) * s_lo[e] + b_lo[e]);
      af[kt][4 + e] = (__bf16)(((va[2 * kt + 1][e] - mu) * rs) * s_hi[e] + b_hi[e]);
    }
  }

  const bf16x8* wa = (const bf16x8*)w1a_f;
  const bf16x8* wb = (const bf16x8*)w1b_f;
  f32x4 acc1[8], acc2[8];
  #pragma unroll
  for (int dt = 0; dt < 8; ++dt) { acc1[dt] = (f32x4){0,0,0,0}; acc2[dt] = (f32x4){0,0,0,0}; }
  #pragma unroll
  for (int dt = 0; dt < 8; ++dt) {
    #pragma unroll
    for (int kt = 0; kt < 4; ++kt) {
      const bf16x8 bfa = wa[(dt * 4 + kt) * 64 + c * 16 + r];
      acc1[dt] = __builtin_amdgcn_mfma_f32_16x16x32_bf16(af[kt], bfa, acc1[dt], 0, 0, 0);
      const bf16x8 bfb = wb[(dt * 4 + kt) * 64 + c * 16 + r];
      acc2[dt] = __builtin_amdgcn_mfma_f32_16x16x32_bf16(af[kt], bfb, acc2[dt], 0, 0, 0);
    }
  }

  float b1v[8];
  #pragma unroll
  for (int dt = 0; dt < 8; ++dt) b1v[dt] = b1[dt * 16 + r];
  #pragma unroll
  for (int j = 0; j < 4; ++j) {
    const int node = node0 + c * 4 + j;
    bf16x8 t1v, t2v;
    #pragma unroll
    for (int dt = 0; dt < 8; ++dt) {
      t1v[dt] = (__bf16)(acc1[dt][j] + b1v[dt]);
      t2v[dt] = (__bf16)acc2[dt][j];
    }
    *(bf16x8*)(t1bp + (size_t)node * 128 + r * 8) = t1v;
    *(bf16x8*)(t2bp + (size_t)node * 128 + r * 8) = t2v;
  }
}

// ---------------------------------------------------------------------------
// K2: edge GEMM, R15 = R13 structure (one node/wave, W1c in block-shared LDS)
// + XOR-swizzled W1c (conflict-free ds_read_b128; swizzle applied on the
// global SOURCE of global_load_lds, LDS dest stays linear — rule #21)
// + bf16 t1 read + bf16 hsum store.
// ---------------------------------------------------------------------------
__global__ __launch_bounds__(256, 4) void k_edge(const float* __restrict__ nbr,
                                                 const int* __restrict__ idx,
                                                 const __bf16* __restrict__ t1bp,
                                                 const __bf16* __restrict__ t2bp,
                                                 const __bf16* __restrict__ w1c_f,
                                                 __bf16* __restrict__ hsum_b) {
  __shared__ __bf16 wlds[8192];                 // 16 KB W1c, swizzled
  const int lane = threadIdx.x & 63;
  const int wid  = threadIdx.x >> 6;
  const int r = lane & 15, c = lane >> 4;

  // ---- stage W1c -> LDS, pre-swizzled source (LDS dest linear: base+lane*16)
  {
    const int s0 = wid * 1024 + lane * 16;
    #pragma unroll
    for (int q = 0; q < 4; ++q) {
      const int s = s0 + q * 4096;
      gload16((const char*)w1c_f + swz(s), (char*)wlds + s);
    }
  }

  // ---- this wave's node: issue all independent loads pre-barrier
  const int n = blockIdx.x * 4 + wid;
  const int4 g = *(const int4*)(idx + n * M_NBR + c * 4);
  const float* arow = nbr + (size_t)n * (M_NBR * E) + r * E + c * 8;
  const f32x4 a0 = *(const f32x4*)(arow);
  const f32x4 a1 = *(const f32x4*)(arow + 4);
  const f32x4 a2 = *(const f32x4*)(arow + 32);
  const f32x4 a3 = *(const f32x4*)(arow + 36);
  const bf16x8 t1v = *(const bf16x8*)(t1bp + (size_t)n * 128 + r * 8);

  __syncthreads();                              // drains W1c stage (vmcnt ✓)

  // ---- gathers (issued now; consumed after the MFMA block)
  const bf16x8 tg0 = *(const bf16x8*)(t2bp + (size_t)g.x * 128 + r * 8);
  const bf16x8 tg1 = *(const bf16x8*)(t2bp + (size_t)g.y * 128 + r * 8);
  const bf16x8 tg2 = *(const bf16x8*)(t2bp + (size_t)g.z * 128 + r * 8);
  const bf16x8 tg3 = *(const bf16x8*)(t2bp + (size_t)g.w * 128 + r * 8);

  // ---- A fragments
  bf16x8 af0, af1;
  #pragma unroll
  for (int e = 0; e < 4; ++e) {
    af0[e] = (__bf16)a0[e]; af0[4 + e] = (__bf16)a1[e];
    af1[e] = (__bf16)a2[e]; af1[4 + e] = (__bf16)a3[e];
  }

  // ---- MFMAs fed from LDS (swizzled read addr matches swizzled store)
  f32x4 acc[8];
  #pragma unroll
  for (int dt = 0; dt < 8; ++dt) acc[dt] = (f32x4){0, 0, 0, 0};
  #pragma unroll
  for (int dt = 0; dt < 8; ++dt) {
    const int o0 = ((dt * 2 + 0) * 64 + c * 16 + r) * 16;
    const int o1 = ((dt * 2 + 1) * 64 + c * 16 + r) * 16;
    const bf16x8 b0 = *(const bf16x8*)((const char*)wlds + swz(o0));
    const bf16x8 b1 = *(const bf16x8*)((const char*)wlds + swz(o1));
    acc[dt] = __builtin_amdgcn_mfma_f32_16x16x32_bf16(af0, b0, acc[dt], 0, 0, 0);
    acc[dt] = __builtin_amdgcn_mfma_f32_16x16x32_bf16(af1, b1, acc[dt], 0, 0, 0);
  }

  // ---- epilogue: +t1(+b1) +t2[g], silu, reduce over c-groups, store bf16
  float ssum[8];
  #pragma unroll
  for (int dt = 0; dt < 8; ++dt) {
    const float tb = (float)t1v[dt];
    float s = 0.f;
    { const float h = acc[dt][0] + tb + (float)tg0[dt]; s += __fdividef(h, 1.0f + __expf(-h)); }
    { const float h = acc[dt][1] + tb + (float)tg1[dt]; s += __fdividef(h, 1.0f + __expf(-h)); }
    { const float h = acc[dt][2] + tb + (float)tg2[dt]; s += __fdividef(h, 1.0f + __expf(-h)); }
    { const float h = acc[dt][3] + tb + (float)tg3[dt]; s += __fdividef(h, 1.0f + __expf(-h)); }
    s += __shfl_xor(s, 16, 64);
    s += __shfl_xor(s, 32, 64);
    ssum[dt] = s;
  }
  if (lane < 16) {
    bf16x8 hs;
    #pragma unroll
    for (int dt = 0; dt < 8; ++dt) hs[dt] = (__bf16)ssum[dt];
    *(bf16x8*)(hsum_b + (size_t)n * 128 + r * 8) = hs;
  }
}

// ---------------------------------------------------------------------------
// K3: out = x + hsum@W2 + 16*b2 via MFMA.  R15: hsum input is bf16 (direct
// A-fragment loads, no cvt — hsum was already bf16-cast here before).
// ---------------------------------------------------------------------------
__global__ __launch_bounds__(256) void k_out(const __bf16* __restrict__ hsum_b,
                                             const __bf16* __restrict__ w2_f,
                                             const float* __restrict__ b2,
                                             const float* __restrict__ x,
                                             float* __restrict__ out) {
  const int wave = blockIdx.x * 4 + (threadIdx.x >> 6);
  if (wave >= N_NODES / 16) return;
  const int lane = threadIdx.x & 63;
  const int r = lane & 15, c = lane >> 4;
  const int node0 = wave * 16;

  const __bf16* row = hsum_b + (size_t)(node0 + r) * 128 + c * 8;
  bf16x8 af[4];
  #pragma unroll
  for (int kt = 0; kt < 4; ++kt) af[kt] = *(const bf16x8*)(row + kt * 32);

  const bf16x8* w2 = (const bf16x8*)w2_f;
  f32x4 acc[8];
  #pragma unroll
  for (int dt = 0; dt < 8; ++dt) acc[dt] = (f32x4){0,0,0,0};
  #pragma unroll
  for (int dt = 0; dt < 8; ++dt) {
    #pragma unroll
    for (int kt = 0; kt < 4; ++kt) {
      const bf16x8 bf = w2[(dt * 4 + kt) * 64 + c * 16 + r];
      acc[dt] = __builtin_amdgcn_mfma_f32_16x16x32_bf16(af[kt], bf, acc[dt], 0, 0, 0);
    }
  }

  float b2v[8];
  #pragma unroll
  for (int dt = 0; dt < 8; ++dt) b2v[dt] = 16.0f * b2[dt * 16 + r];
  #pragma unroll
  for (int j = 0; j < 4; ++j) {
    const int node = node0 + c * 4 + j;
    #pragma unroll
    for (int dt = 0; dt < 8; ++dt) {
      const size_t o = (size_t)node * 128 + dt * 16 + r;
      out[o] = x[o] + acc[dt][j] + b2v[dt];
    }
  }
}

// ---------------------------------------------------------------------------
extern "C" void kernel_launch(void* const* d_in, const int* in_sizes, int n_in,
                              void* d_out, int out_size, void* d_ws, size_t ws_size,
                              hipStream_t stream) {
  const float* x        = (const float*)d_in[0];
  const float* nbr_fea  = (const float*)d_in[1];
  const int*   nbr_idx  = (const int*)d_in[2];
  const float* ln_scale = (const float*)d_in[3];
  const float* ln_bias  = (const float*)d_in[4];
  const float* W1       = (const float*)d_in[5];
  const float* b1       = (const float*)d_in[6];
  const float* W2       = (const float*)d_in[7];
  const float* b2       = (const float*)d_in[8];
  float* out = (float*)d_out;

  char* ws = (char*)d_ws;
  __bf16* t1bp   = (__bf16*)(ws);                      // 12,800,000 B
  __bf16* hsum_b = (__bf16*)(ws + 12800000);           // 12,800,000 B
  __bf16* t2bp   = (__bf16*)(ws + 25600000);           // 12,800,000 B
  __bf16* w1a_f  = (__bf16*)(ws + 38400000);           //     32,768 B
  __bf16* w1b_f  = (__bf16*)(ws + 38433536);           //  (aligned) 32,768 B
  __bf16* w1c_f  = (__bf16*)(ws + 38466304);           //     16,384 B
  __bf16* w2_f   = (__bf16*)(ws + 38482688);           //     32,768 B

  k_prep <<<224, 256, 0, stream>>>(W1, W2, w1a_f, w1b_f, w1c_f, w2_f);
  k_t12f <<<(N_NODES / 16 + 3) / 4, 256, 0, stream>>>(x, ln_scale, ln_bias,
                                                      w1a_f, w1b_f, b1, t1bp, t2bp);
  k_edge <<<N_NODES / 4, 256, 0, stream>>>(nbr_fea, nbr_idx, t1bp, t2bp, w1c_f, hsum_b);
  k_out  <<<(N_NODES / 16 + 3) / 4, 256, 0, stream>>>(hsum_b, w2_f, b2, x, out);
}

// Round 16
// 120.014 us; speedup vs baseline: 1.3352x; 1.0225x over previous
//
#include <hip/hip_runtime.h>
#include <math.h>

#define N_NODES 50000
#define M_NBR 16
#define D 128
#define E 64

typedef __attribute__((ext_vector_type(8))) __bf16 bf16x8;
typedef __attribute__((ext_vector_type(4))) float f32x4;

// async global->LDS (HW: per-lane global src; wave-uniform LDS base + lane*16)
__device__ __forceinline__ void gload16(const void* g, void* l) {
  __builtin_amdgcn_global_load_lds(
      (const __attribute__((address_space(1))) void*)g,
      (__attribute__((address_space(3))) void*)l, 16, 0, 0);
}

// W1c LDS swizzle: stored[s] = orig[s ^ (((s>>7)&7)<<4)]  (involution; XORs
// bits {7,8,9} = {r3,c0,c1} into bank bits {4,5,6} -> conflict-free b128 reads)
__device__ __forceinline__ int swz(int o) { return o ^ (((o >> 7) & 7) << 4); }

// Fragment-permuted weight storage (bf16):
//   flat = (((dt*NKT + kt)*4 + c)*16 + r)*8 + j
// holds W_natural[k = kt*32 + c*8 + j][d = dt*16 + r].

// ---------------------------------------------------------------------------
// K0: build fragment-permuted bf16 weights.
// R16: W2 region now NATURAL k-order (hsum is consumed in natural-d layout
// from LDS inside the fused kernel; the old k-remap compensated the permuted
// global hsum layout which no longer exists).
// ---------------------------------------------------------------------------
__global__ __launch_bounds__(256) void k_prep(const float* __restrict__ W1,
                                              const float* __restrict__ W2,
                                              __bf16* __restrict__ w1a_f,
                                              __bf16* __restrict__ w1b_f,
                                              __bf16* __restrict__ w1c_f,
                                              __bf16* __restrict__ w2_f) {
  const int t = blockIdx.x * 256 + threadIdx.x;
  if (t < 16384) {                       // W1a
    const int j = t & 7, r = (t >> 3) & 15, c = (t >> 7) & 3, q = t >> 9;
    const int kt = q & 3, dt = q >> 2;
    w1a_f[t] = (__bf16)W1[(kt * 32 + c * 8 + j) * 128 + dt * 16 + r];
  } else if (t < 32768) {                // W1b
    const int u = t - 16384;
    const int j = u & 7, r = (u >> 3) & 15, c = (u >> 7) & 3, q = u >> 9;
    const int kt = q & 3, dt = q >> 2;
    w1b_f[u] = (__bf16)W1[(128 + kt * 32 + c * 8 + j) * 128 + dt * 16 + r];
  } else if (t < 40960) {                // W1c (NKT=2)
    const int u = t - 32768;
    const int j = u & 7, r = (u >> 3) & 15, c = (u >> 7) & 3, q = u >> 9;
    const int kt = q & 1, dt = q >> 1;
    w1c_f[u] = (__bf16)W1[(256 + kt * 32 + c * 8 + j) * 128 + dt * 16 + r];
  } else if (t < 57344) {                // W2, NATURAL k
    const int u = t - 40960;
    const int j = u & 7, r = (u >> 3) & 15, c = (u >> 7) & 3, q = u >> 9;
    const int kt = q & 3, dt = q >> 2;
    w2_f[u] = (__bf16)W2[(kt * 32 + c * 8 + j) * 128 + dt * 16 + r];
  }
}

// ---------------------------------------------------------------------------
// K1: fused LayerNorm + dual GEMM via MFMA.  (unchanged from R15, known-good)
// ---------------------------------------------------------------------------
__global__ __launch_bounds__(256) void k_t12f(const float* __restrict__ x,
                                              const float* __restrict__ sc,
                                              const float* __restrict__ bi,
                                              const __bf16* __restrict__ w1a_f,
                                              const __bf16* __restrict__ w1b_f,
                                              const float* __restrict__ b1,
                                              __bf16* __restrict__ t1bp,
                                              __bf16* __restrict__ t2bp) {
  const int wave = blockIdx.x * 4 + (threadIdx.x >> 6);
  if (wave >= N_NODES / 16) return;
  const int lane = threadIdx.x & 63;
  const int r = lane & 15, c = lane >> 4;
  const int node0 = wave * 16;

  const float* row = x + (size_t)(node0 + r) * 128 + c * 8;
  f32x4 va[8];
  #pragma unroll
  for (int kt = 0; kt < 4; ++kt) {
    va[2 * kt]     = *(const f32x4*)(row + kt * 32);
    va[2 * kt + 1] = *(const f32x4*)(row + kt * 32 + 4);
  }
  float s = 0.f;
  #pragma unroll
  for (int q = 0; q < 8; ++q) s += va[q][0] + va[q][1] + va[q][2] + va[q][3];
  s += __shfl_xor(s, 16, 64);
  s += __shfl_xor(s, 32, 64);
  const float mu = s * (1.0f / 128.0f);
  float qs = 0.f;
  #pragma unroll
  for (int q = 0; q < 8; ++q) {
    #pragma unroll
    for (int e = 0; e < 4; ++e) { const float dxx = va[q][e] - mu; qs += dxx * dxx; }
  }
  qs += __shfl_xor(qs, 16, 64);
  qs += __shfl_xor(qs, 32, 64);
  const float rs = rsqrtf(qs * (1.0f / 128.0f) + 1e-6f);

  bf16x8 af[4];
  #pragma unroll
  for (int kt = 0; kt < 4; ++kt) {
    const f32x4 s_lo = *(const f32x4*)(sc + kt * 32 + c * 8);
    const f32x4 s_hi = *(const f32x4*)(sc + kt * 32 + c * 8 + 4);
    const f32x4 b_lo = *(const f32x4*)(bi + kt * 32 + c * 8);
    const f32x4 b_hi = *(const f32x4*)(bi + kt * 32 + c * 8 + 4);
    #pragma unroll
    for (int e = 0; e < 4; ++e) {
      af[kt][e]     = (__bf16)(((va[2 * kt][e]     - mu) * rs) * s_lo[e] + b_lo[e]);
      af[kt][4 + e] = (__bf16)(((va[2 * kt + 1][e] - mu) * rs) * s_hi[e] + b_hi[e]);
    }
  }

  const bf16x8* wa = (const bf16x8*)w1a_f;
  const bf16x8* wb = (const bf16x8*)w1b_f;
  f32x4 acc1[8], acc2[8];
  #pragma unroll
  for (int dt = 0; dt < 8; ++dt) { acc1[dt] = (f32x4){0,0,0,0}; acc2[dt] = (f32x4){0,0,0,0}; }
  #pragma unroll
  for (int dt = 0; dt < 8; ++dt) {
    #pragma unroll
    for (int kt = 0; kt < 4; ++kt) {
      const bf16x8 bfa = wa[(dt * 4 + kt) * 64 + c * 16 + r];
      acc1[dt] = __builtin_amdgcn_mfma_f32_16x16x32_bf16(af[kt], bfa, acc1[dt], 0, 0, 0);
      const bf16x8 bfb = wb[(dt * 4 + kt) * 64 + c * 16 + r];
      acc2[dt] = __builtin_amdgcn_mfma_f32_16x16x32_bf16(af[kt], bfb, acc2[dt], 0, 0, 0);
    }
  }

  float b1v[8];
  #pragma unroll
  for (int dt = 0; dt < 8; ++dt) b1v[dt] = b1[dt * 16 + r];
  #pragma unroll
  for (int j = 0; j < 4; ++j) {
    const int node = node0 + c * 4 + j;
    bf16x8 t1v, t2v;
    #pragma unroll
    for (int dt = 0; dt < 8; ++dt) {
      t1v[dt] = (__bf16)(acc1[dt][j] + b1v[dt]);
      t2v[dt] = (__bf16)acc2[dt][j];
    }
    *(bf16x8*)(t1bp + (size_t)node * 128 + r * 8) = t1v;
    *(bf16x8*)(t2bp + (size_t)node * 128 + r * 8) = t2v;
  }
}

// ---------------------------------------------------------------------------
// K2 (fused): edge GEMM + silu + m-sum  ->  LDS hsum tile  ->  W2 GEMM +
// residual + store.  Block = 256 thr = 4 waves = 16 nodes (one k_out tile).
// Phase 1: stage swizzled W1c -> LDS.
// Phase 2: per wave, 4 nodes serial (R15 per-node flow); ssum -> hlds
//          [16][136] bf16 (pitch-padded: writes & reads <=2-way conflicts).
// Phase 3: W2 GEMM — wave wid owns dt = {2*wid, 2*wid+1}; A-frags from hlds
//          (natural-k), B-frags direct from L2-hot w2_f; out = x + acc +16*b2.
// ---------------------------------------------------------------------------
#define HPITCH 136

__global__ __launch_bounds__(256, 4) void k_edge2(const float* __restrict__ nbr,
                                                  const int* __restrict__ idx,
                                                  const __bf16* __restrict__ t1bp,
                                                  const __bf16* __restrict__ t2bp,
                                                  const __bf16* __restrict__ w1c_f,
                                                  const __bf16* __restrict__ w2_f,
                                                  const float* __restrict__ b2,
                                                  const float* __restrict__ x,
                                                  float* __restrict__ out) {
  __shared__ __bf16 wlds[8192];            // 16 KB W1c, swizzled
  __shared__ __bf16 hlds[16 * HPITCH];     // 4.25 KB hsum tile, natural d
  const int lane = threadIdx.x & 63;
  const int wid  = threadIdx.x >> 6;
  const int r = lane & 15, c = lane >> 4;
  const int nb0 = blockIdx.x * 16;

  // ---- phase 1: stage W1c (pre-swizzled source; LDS dest linear)
  {
    const int s0 = wid * 1024 + lane * 16;
    #pragma unroll
    for (int q = 0; q < 4; ++q) {
      const int s = s0 + q * 4096;
      gload16((const char*)w1c_f + swz(s), (char*)wlds + s);
    }
  }
  __syncthreads();                          // W1c resident (drains vmcnt)

  // ---- phase 2: 4 nodes per wave, serial; fully static indexing
  #pragma unroll
  for (int i = 0; i < 4; ++i) {
    const int row = wid * 4 + i;            // tile row 0..15
    const int n = nb0 + row;

    const int4 g = *(const int4*)(idx + n * M_NBR + c * 4);
    const float* arow = nbr + (size_t)n * (M_NBR * E) + r * E + c * 8;
    const f32x4 a0 = *(const f32x4*)(arow);
    const f32x4 a1 = *(const f32x4*)(arow + 4);
    const f32x4 a2 = *(const f32x4*)(arow + 32);
    const f32x4 a3 = *(const f32x4*)(arow + 36);
    const bf16x8 t1v = *(const bf16x8*)(t1bp + (size_t)n * 128 + r * 8);
    const bf16x8 tg0 = *(const bf16x8*)(t2bp + (size_t)g.x * 128 + r * 8);
    const bf16x8 tg1 = *(const bf16x8*)(t2bp + (size_t)g.y * 128 + r * 8);
    const bf16x8 tg2 = *(const bf16x8*)(t2bp + (size_t)g.z * 128 + r * 8);
    const bf16x8 tg3 = *(const bf16x8*)(t2bp + (size_t)g.w * 128 + r * 8);

    bf16x8 af0, af1;
    #pragma unroll
    for (int e = 0; e < 4; ++e) {
      af0[e] = (__bf16)a0[e]; af0[4 + e] = (__bf16)a1[e];
      af1[e] = (__bf16)a2[e]; af1[4 + e] = (__bf16)a3[e];
    }

    f32x4 acc[8];
    #pragma unroll
    for (int dt = 0; dt < 8; ++dt) acc[dt] = (f32x4){0, 0, 0, 0};
    #pragma unroll
    for (int dt = 0; dt < 8; ++dt) {
      const int o0 = ((dt * 2 + 0) * 64 + c * 16 + r) * 16;
      const int o1 = ((dt * 2 + 1) * 64 + c * 16 + r) * 16;
      const bf16x8 b0 = *(const bf16x8*)((const char*)wlds + swz(o0));
      const bf16x8 b1 = *(const bf16x8*)((const char*)wlds + swz(o1));
      acc[dt] = __builtin_amdgcn_mfma_f32_16x16x32_bf16(af0, b0, acc[dt], 0, 0, 0);
      acc[dt] = __builtin_amdgcn_mfma_f32_16x16x32_bf16(af1, b1, acc[dt], 0, 0, 0);
    }

    #pragma unroll
    for (int dt = 0; dt < 8; ++dt) {
      const float tb = (float)t1v[dt];
      float s = 0.f;
      { const float h = acc[dt][0] + tb + (float)tg0[dt]; s += __fdividef(h, 1.0f + __expf(-h)); }
      { const float h = acc[dt][1] + tb + (float)tg1[dt]; s += __fdividef(h, 1.0f + __expf(-h)); }
      { const float h = acc[dt][2] + tb + (float)tg2[dt]; s += __fdividef(h, 1.0f + __expf(-h)); }
      { const float h = acc[dt][3] + tb + (float)tg3[dt]; s += __fdividef(h, 1.0f + __expf(-h)); }
      s += __shfl_xor(s, 16, 64);
      s += __shfl_xor(s, 32, 64);
      if (lane < 16) hlds[row * HPITCH + dt * 16 + lane] = (__bf16)s;
    }
  }
  __syncthreads();                          // hsum tile resident

  // ---- phase 3: W2 GEMM for this block's 16 nodes; wave owns 2 dt-tiles
  const int dtA = wid * 2, dtB = wid * 2 + 1;
  const bf16x8* w2 = (const bf16x8*)w2_f;
  bf16x8 bA[4], bB[4];
  #pragma unroll
  for (int kt = 0; kt < 4; ++kt) {
    bA[kt] = w2[(dtA * 4 + kt) * 64 + c * 16 + r];
    bB[kt] = w2[(dtB * 4 + kt) * 64 + c * 16 + r];
  }
  bf16x8 haf[4];
  #pragma unroll
  for (int kt = 0; kt < 4; ++kt)
    haf[kt] = *(const bf16x8*)(hlds + r * HPITCH + kt * 32 + c * 8);

  f32x4 accA = (f32x4){0,0,0,0}, accB = (f32x4){0,0,0,0};
  #pragma unroll
  for (int kt = 0; kt < 4; ++kt) {
    accA = __builtin_amdgcn_mfma_f32_16x16x32_bf16(haf[kt], bA[kt], accA, 0, 0, 0);
    accB = __builtin_amdgcn_mfma_f32_16x16x32_bf16(haf[kt], bB[kt], accB, 0, 0, 0);
  }

  const float b2A = 16.0f * b2[dtA * 16 + r];
  const float b2B = 16.0f * b2[dtB * 16 + r];
  #pragma unroll
  for (int j = 0; j < 4; ++j) {
    const int node = nb0 + c * 4 + j;
    const size_t oA = (size_t)node * 128 + dtA * 16 + r;
    const size_t oB = (size_t)node * 128 + dtB * 16 + r;
    out[oA] = x[oA] + accA[j] + b2A;
    out[oB] = x[oB] + accB[j] + b2B;
  }
}

// ---------------------------------------------------------------------------
extern "C" void kernel_launch(void* const* d_in, const int* in_sizes, int n_in,
                              void* d_out, int out_size, void* d_ws, size_t ws_size,
                              hipStream_t stream) {
  const float* x        = (const float*)d_in[0];
  const float* nbr_fea  = (const float*)d_in[1];
  const int*   nbr_idx  = (const int*)d_in[2];
  const float* ln_scale = (const float*)d_in[3];
  const float* ln_bias  = (const float*)d_in[4];
  const float* W1       = (const float*)d_in[5];
  const float* b1       = (const float*)d_in[6];
  const float* W2       = (const float*)d_in[7];
  const float* b2       = (const float*)d_in[8];
  float* out = (float*)d_out;

  char* ws = (char*)d_ws;
  __bf16* t1bp   = (__bf16*)(ws);                      // 12,800,000 B
  __bf16* t2bp   = (__bf16*)(ws + 12800000);           // 12,800,000 B
  __bf16* w1a_f  = (__bf16*)(ws + 25600000);           //     32,768 B
  __bf16* w1b_f  = (__bf16*)(ws + 25632768);           //     32,768 B
  __bf16* w1c_f  = (__bf16*)(ws + 25665536);           //     16,384 B
  __bf16* w2_f   = (__bf16*)(ws + 25681920);           //     32,768 B

  k_prep  <<<224, 256, 0, stream>>>(W1, W2, w1a_f, w1b_f, w1c_f, w2_f);
  k_t12f  <<<(N_NODES / 16 + 3) / 4, 256, 0, stream>>>(x, ln_scale, ln_bias,
                                                       w1a_f, w1b_f, b1, t1bp, t2bp);
  k_edge2 <<<N_NODES / 16, 256, 0, stream>>>(nbr_fea, nbr_idx, t1bp, t2bp,
                                             w1c_f, w2_f, b2, x, out);
}

// Round 17
// 114.678 us; speedup vs baseline: 1.3974x; 1.0465x over previous
//
#include <hip/hip_runtime.h>
#include <math.h>

#define N_NODES 50000
#define M_NBR 16
#define D 128
#define E 64

typedef __attribute__((ext_vector_type(8))) __bf16 bf16x8;
typedef __attribute__((ext_vector_type(4))) float f32x4;

// async global->LDS (HW: per-lane global src; wave-uniform LDS base + lane*16)
__device__ __forceinline__ void gload16(const void* g, void* l) {
  __builtin_amdgcn_global_load_lds(
      (const __attribute__((address_space(1))) void*)g,
      (__attribute__((address_space(3))) void*)l, 16, 0, 0);
}

// Memory-clobber fence: memory ops cannot legally cross (unlike sched_barrier,
// which the scheduler ignored for load sinking in R8/R14).  Compiler's own
// per-register counted vmcnt waits handle correctness without draining.
#define FENCE() asm volatile("" ::: "memory")

// W1c LDS swizzle: stored[s] = orig[s ^ (((s>>7)&7)<<4)]  (involution)
__device__ __forceinline__ int swz(int o) { return o ^ (((o >> 7) & 7) << 4); }

// Fragment-permuted weight storage (bf16):
//   flat = (((dt*NKT + kt)*4 + c)*16 + r)*8 + j
// holds W_natural[k = kt*32 + c*8 + j][d = dt*16 + r].

// ---------------------------------------------------------------------------
// K0: build fragment-permuted bf16 weights.  (unchanged, known-good; W2 natural-k)
// ---------------------------------------------------------------------------
__global__ __launch_bounds__(256) void k_prep(const float* __restrict__ W1,
                                              const float* __restrict__ W2,
                                              __bf16* __restrict__ w1a_f,
                                              __bf16* __restrict__ w1b_f,
                                              __bf16* __restrict__ w1c_f,
                                              __bf16* __restrict__ w2_f) {
  const int t = blockIdx.x * 256 + threadIdx.x;
  if (t < 16384) {                       // W1a
    const int j = t & 7, r = (t >> 3) & 15, c = (t >> 7) & 3, q = t >> 9;
    const int kt = q & 3, dt = q >> 2;
    w1a_f[t] = (__bf16)W1[(kt * 32 + c * 8 + j) * 128 + dt * 16 + r];
  } else if (t < 32768) {                // W1b
    const int u = t - 16384;
    const int j = u & 7, r = (u >> 3) & 15, c = (u >> 7) & 3, q = u >> 9;
    const int kt = q & 3, dt = q >> 2;
    w1b_f[u] = (__bf16)W1[(128 + kt * 32 + c * 8 + j) * 128 + dt * 16 + r];
  } else if (t < 40960) {                // W1c (NKT=2)
    const int u = t - 32768;
    const int j = u & 7, r = (u >> 3) & 15, c = (u >> 7) & 3, q = u >> 9;
    const int kt = q & 1, dt = q >> 1;
    w1c_f[u] = (__bf16)W1[(256 + kt * 32 + c * 8 + j) * 128 + dt * 16 + r];
  } else if (t < 57344) {                // W2, NATURAL k
    const int u = t - 40960;
    const int j = u & 7, r = (u >> 3) & 15, c = (u >> 7) & 3, q = u >> 9;
    const int kt = q & 3, dt = q >> 2;
    w2_f[u] = (__bf16)W2[(kt * 32 + c * 8 + j) * 128 + dt * 16 + r];
  }
}

// ---------------------------------------------------------------------------
// K1: fused LayerNorm + dual GEMM via MFMA.  (unchanged, known-good)
// ---------------------------------------------------------------------------
__global__ __launch_bounds__(256) void k_t12f(const float* __restrict__ x,
                                              const float* __restrict__ sc,
                                              const float* __restrict__ bi,
                                              const __bf16* __restrict__ w1a_f,
                                              const __bf16* __restrict__ w1b_f,
                                              const float* __restrict__ b1,
                                              __bf16* __restrict__ t1bp,
                                              __bf16* __restrict__ t2bp) {
  const int wave = blockIdx.x * 4 + (threadIdx.x >> 6);
  if (wave >= N_NODES / 16) return;
  const int lane = threadIdx.x & 63;
  const int r = lane & 15, c = lane >> 4;
  const int node0 = wave * 16;

  const float* row = x + (size_t)(node0 + r) * 128 + c * 8;
  f32x4 va[8];
  #pragma unroll
  for (int kt = 0; kt < 4; ++kt) {
    va[2 * kt]     = *(const f32x4*)(row + kt * 32);
    va[2 * kt + 1] = *(const f32x4*)(row + kt * 32 + 4);
  }
  float s = 0.f;
  #pragma unroll
  for (int q = 0; q < 8; ++q) s += va[q][0] + va[q][1] + va[q][2] + va[q][3];
  s += __shfl_xor(s, 16, 64);
  s += __shfl_xor(s, 32, 64);
  const float mu = s * (1.0f / 128.0f);
  float qs = 0.f;
  #pragma unroll
  for (int q = 0; q < 8; ++q) {
    #pragma unroll
    for (int e = 0; e < 4; ++e) { const float dxx = va[q][e] - mu; qs += dxx * dxx; }
  }
  qs += __shfl_xor(qs, 16, 64);
  qs += __shfl_xor(qs, 32, 64);
  const float rs = rsqrtf(qs * (1.0f / 128.0f) + 1e-6f);

  bf16x8 af[4];
  #pragma unroll
  for (int kt = 0; kt < 4; ++kt) {
    const f32x4 s_lo = *(const f32x4*)(sc + kt * 32 + c * 8);
    const f32x4 s_hi = *(const f32x4*)(sc + kt * 32 + c * 8 + 4);
    const f32x4 b_lo = *(const f32x4*)(bi + kt * 32 + c * 8);
    const f32x4 b_hi = *(const f32x4*)(bi + kt * 32 + c * 8 + 4);
    #pragma unroll
    for (int e = 0; e < 4; ++e) {
      af[kt][e]     = (__bf16)(((va[2 * kt][e]     - mu) * rs) * s_lo[e] + b_lo[e]);
      af[kt][4 + e] = (__bf16)(((va[2 * kt + 1][e] - mu) * rs) * s_hi[e] + b_hi[e]);
    }
  }

  const bf16x8* wa = (const bf16x8*)w1a_f;
  const bf16x8* wb = (const bf16x8*)w1b_f;
  f32x4 acc1[8], acc2[8];
  #pragma unroll
  for (int dt = 0; dt < 8; ++dt) { acc1[dt] = (f32x4){0,0,0,0}; acc2[dt] = (f32x4){0,0,0,0}; }
  #pragma unroll
  for (int dt = 0; dt < 8; ++dt) {
    #pragma unroll
    for (int kt = 0; kt < 4; ++kt) {
      const bf16x8 bfa = wa[(dt * 4 + kt) * 64 + c * 16 + r];
      acc1[dt] = __builtin_amdgcn_mfma_f32_16x16x32_bf16(af[kt], bfa, acc1[dt], 0, 0, 0);
      const bf16x8 bfb = wb[(dt * 4 + kt) * 64 + c * 16 + r];
      acc2[dt] = __builtin_amdgcn_mfma_f32_16x16x32_bf16(af[kt], bfb, acc2[dt], 0, 0, 0);
    }
  }

  float b1v[8];
  #pragma unroll
  for (int dt = 0; dt < 8; ++dt) b1v[dt] = b1[dt * 16 + r];
  #pragma unroll
  for (int j = 0; j < 4; ++j) {
    const int node = node0 + c * 4 + j;
    bf16x8 t1v, t2v;
    #pragma unroll
    for (int dt = 0; dt < 8; ++dt) {
      t1v[dt] = (__bf16)(acc1[dt][j] + b1v[dt]);
      t2v[dt] = (__bf16)acc2[dt][j];
    }
    *(bf16x8*)(t1bp + (size_t)node * 128 + r * 8) = t1v;
    *(bf16x8*)(t2bp + (size_t)node * 128 + r * 8) = t2v;
  }
}

// ---------------------------------------------------------------------------
// K2 (fused), R17: phase-2 is a 2-deep VGPR-staged pipeline with memory-
// clobber fences.  W1c in LDS (read-only after one barrier); phase-2 stores
// go to LDS (no VMEM stores in the loop); 9 VMEM loads/node to named VGPRs.
// load(i+1) pinned above compute(i) by FENCE(); compiler emits accurate
// counted per-register vmcnt waits (no vmcnt(0) drain: no ds_read-after-DMA
// hazard in the loop).
// ---------------------------------------------------------------------------
#define HPITCH 136

struct NL {
  f32x4 a0, a1, a2, a3;          // nbr A-row pieces (fp32)
  bf16x8 t1v;                    // t1 row (b1 folded)
  bf16x8 tg0, tg1, tg2, tg3;     // gathered t2 rows
};

__device__ __forceinline__ NL load_node(const float* __restrict__ nbr,
                                        const __bf16* __restrict__ t1bp,
                                        const __bf16* __restrict__ t2bp,
                                        int n, int4 g, int r, int c) {
  NL v;
  const float* arow = nbr + (size_t)n * (M_NBR * E) + r * E + c * 8;
  v.a0 = *(const f32x4*)(arow);
  v.a1 = *(const f32x4*)(arow + 4);
  v.a2 = *(const f32x4*)(arow + 32);
  v.a3 = *(const f32x4*)(arow + 36);
  v.t1v = *(const bf16x8*)(t1bp + (size_t)n * 128 + r * 8);
  v.tg0 = *(const bf16x8*)(t2bp + (size_t)g.x * 128 + r * 8);
  v.tg1 = *(const bf16x8*)(t2bp + (size_t)g.y * 128 + r * 8);
  v.tg2 = *(const bf16x8*)(t2bp + (size_t)g.z * 128 + r * 8);
  v.tg3 = *(const bf16x8*)(t2bp + (size_t)g.w * 128 + r * 8);
  return v;
}

__device__ __forceinline__ void compute_node(const NL& v, const __bf16* wlds,
                                             __bf16* hlds, int row,
                                             int lane, int r, int c) {
  bf16x8 af0, af1;
  #pragma unroll
  for (int e = 0; e < 4; ++e) {
    af0[e] = (__bf16)v.a0[e]; af0[4 + e] = (__bf16)v.a1[e];
    af1[e] = (__bf16)v.a2[e]; af1[4 + e] = (__bf16)v.a3[e];
  }
  f32x4 acc[8];
  #pragma unroll
  for (int dt = 0; dt < 8; ++dt) acc[dt] = (f32x4){0, 0, 0, 0};
  #pragma unroll
  for (int dt = 0; dt < 8; ++dt) {
    const int o0 = ((dt * 2 + 0) * 64 + c * 16 + r) * 16;
    const int o1 = ((dt * 2 + 1) * 64 + c * 16 + r) * 16;
    const bf16x8 b0 = *(const bf16x8*)((const char*)wlds + swz(o0));
    const bf16x8 b1 = *(const bf16x8*)((const char*)wlds + swz(o1));
    acc[dt] = __builtin_amdgcn_mfma_f32_16x16x32_bf16(af0, b0, acc[dt], 0, 0, 0);
    acc[dt] = __builtin_amdgcn_mfma_f32_16x16x32_bf16(af1, b1, acc[dt], 0, 0, 0);
  }
  #pragma unroll
  for (int dt = 0; dt < 8; ++dt) {
    const float tb = (float)v.t1v[dt];
    float s = 0.f;
    { const float h = acc[dt][0] + tb + (float)v.tg0[dt]; s += __fdividef(h, 1.0f + __expf(-h)); }
    { const float h = acc[dt][1] + tb + (float)v.tg1[dt]; s += __fdividef(h, 1.0f + __expf(-h)); }
    { const float h = acc[dt][2] + tb + (float)v.tg2[dt]; s += __fdividef(h, 1.0f + __expf(-h)); }
    { const float h = acc[dt][3] + tb + (float)v.tg3[dt]; s += __fdividef(h, 1.0f + __expf(-h)); }
    s += __shfl_xor(s, 16, 64);
    s += __shfl_xor(s, 32, 64);
    if (lane < 16) hlds[row * HPITCH + dt * 16 + lane] = (__bf16)s;
  }
}

__global__ __launch_bounds__(256, 3) void k_edge2(const float* __restrict__ nbr,
                                                  const int* __restrict__ idx,
                                                  const __bf16* __restrict__ t1bp,
                                                  const __bf16* __restrict__ t2bp,
                                                  const __bf16* __restrict__ w1c_f,
                                                  const __bf16* __restrict__ w2_f,
                                                  const float* __restrict__ b2,
                                                  const float* __restrict__ x,
                                                  float* __restrict__ out) {
  __shared__ __bf16 wlds[8192];            // 16 KB W1c, swizzled
  __shared__ __bf16 hlds[16 * HPITCH];     // 4.25 KB hsum tile, natural d
  const int lane = threadIdx.x & 63;
  const int wid  = threadIdx.x >> 6;
  const int r = lane & 15, c = lane >> 4;
  const int nb0 = blockIdx.x * 16;
  const int row0 = wid * 4;

  // ---- phase 1: stage W1c (pre-swizzled source; LDS dest linear)
  {
    const int s0 = wid * 1024 + lane * 16;
    #pragma unroll
    for (int q = 0; q < 4; ++q) {
      const int s = s0 + q * 4096;
      gload16((const char*)w1c_f + swz(s), (char*)wlds + s);
    }
  }

  // idx for all 4 nodes (pre-barrier, overlaps W1c stage)
  const int4 g0 = *(const int4*)(idx + (nb0 + row0 + 0) * M_NBR + c * 4);
  const int4 g1 = *(const int4*)(idx + (nb0 + row0 + 1) * M_NBR + c * 4);
  const int4 g2 = *(const int4*)(idx + (nb0 + row0 + 2) * M_NBR + c * 4);
  const int4 g3 = *(const int4*)(idx + (nb0 + row0 + 3) * M_NBR + c * 4);

  __syncthreads();                          // W1c resident (one-time drain)

  // ---- phase 2: 2-deep VGPR pipeline over this wave's 4 nodes
  NL va = load_node(nbr, t1bp, t2bp, nb0 + row0 + 0, g0, r, c);
  NL vb = load_node(nbr, t1bp, t2bp, nb0 + row0 + 1, g1, r, c);
  FENCE();
  compute_node(va, wlds, hlds, row0 + 0, lane, r, c);

  va = load_node(nbr, t1bp, t2bp, nb0 + row0 + 2, g2, r, c);
  FENCE();
  compute_node(vb, wlds, hlds, row0 + 1, lane, r, c);

  vb = load_node(nbr, t1bp, t2bp, nb0 + row0 + 3, g3, r, c);
  FENCE();
  compute_node(va, wlds, hlds, row0 + 2, lane, r, c);
  compute_node(vb, wlds, hlds, row0 + 3, lane, r, c);

  __syncthreads();                          // hsum tile resident

  // ---- phase 3: W2 GEMM for this block's 16 nodes; wave owns 2 dt-tiles
  const int dtA = wid * 2, dtB = wid * 2 + 1;
  const bf16x8* w2 = (const bf16x8*)w2_f;
  bf16x8 bA[4], bB[4];
  #pragma unroll
  for (int kt = 0; kt < 4; ++kt) {
    bA[kt] = w2[(dtA * 4 + kt) * 64 + c * 16 + r];
    bB[kt] = w2[(dtB * 4 + kt) * 64 + c * 16 + r];
  }
  bf16x8 haf[4];
  #pragma unroll
  for (int kt = 0; kt < 4; ++kt)
    haf[kt] = *(const bf16x8*)(hlds + r * HPITCH + kt * 32 + c * 8);

  f32x4 accA = (f32x4){0,0,0,0}, accB = (f32x4){0,0,0,0};
  #pragma unroll
  for (int kt = 0; kt < 4; ++kt) {
    accA = __builtin_amdgcn_mfma_f32_16x16x32_bf16(haf[kt], bA[kt], accA, 0, 0, 0);
    accB = __builtin_amdgcn_mfma_f32_16x16x32_bf16(haf[kt], bB[kt], accB, 0, 0, 0);
  }

  const float b2A = 16.0f * b2[dtA * 16 + r];
  const float b2B = 16.0f * b2[dtB * 16 + r];
  #pragma unroll
  for (int j = 0; j < 4; ++j) {
    const int node = nb0 + c * 4 + j;
    const size_t oA = (size_t)node * 128 + dtA * 16 + r;
    const size_t oB = (size_t)node * 128 + dtB * 16 + r;
    out[oA] = x[oA] + accA[j] + b2A;
    out[oB] = x[oB] + accB[j] + b2B;
  }
}

// ---------------------------------------------------------------------------
extern "C" void kernel_launch(void* const* d_in, const int* in_sizes, int n_in,
                              void* d_out, int out_size, void* d_ws, size_t ws_size,
                              hipStream_t stream) {
  const float* x        = (const float*)d_in[0];
  const float* nbr_fea  = (const float*)d_in[1];
  const int*   nbr_idx  = (const int*)d_in[2];
  const float* ln_scale = (const float*)d_in[3];
  const float* ln_bias  = (const float*)d_in[4];
  const float* W1       = (const float*)d_in[5];
  const float* b1       = (const float*)d_in[6];
  const float* W2       = (const float*)d_in[7];
  const float* b2       = (const float*)d_in[8];
  float* out = (float*)d_out;

  char* ws = (char*)d_ws;
  __bf16* t1bp   = (__bf16*)(ws);                      // 12,800,000 B
  __bf16* t2bp   = (__bf16*)(ws + 12800000);           // 12,800,000 B
  __bf16* w1a_f  = (__bf16*)(ws + 25600000);           //     32,768 B
  __bf16* w1b_f  = (__bf16*)(ws + 25632768);           //     32,768 B
  __bf16* w1c_f  = (__bf16*)(ws + 25665536);           //     16,384 B
  __bf16* w2_f   = (__bf16*)(ws + 25681920);           //     32,768 B

  k_prep  <<<224, 256, 0, stream>>>(W1, W2, w1a_f, w1b_f, w1c_f, w2_f);
  k_t12f  <<<(N_NODES / 16 + 3) / 4, 256, 0, stream>>>(x, ln_scale, ln_bias,
                                                       w1a_f, w1b_f, b1, t1bp, t2bp);
  k_edge2 <<<N_NODES / 16, 256, 0, stream>>>(nbr_fea, nbr_idx, t1bp, t2bp,
                                             w1c_f, w2_f, b2, x, out);
}